// Round 5
// baseline (886.792 us; speedup 1.0000x reference)
//
#include <hip/hip_runtime.h>
#include <hip/hip_fp16.h>
#include <hip/hip_cooperative_groups.h>

namespace cg = cooperative_groups;

#define EPS 1e-7f
// ONE cooperative kernel replaces {memset, part, build, main, gemm}: the
// ~10us/boundary dispatch-drain gaps (5-6 of them) were the dominant
// non-work cost. Dataflow inside is byte-identical to the proven R0 path:
// 256-node buckets, partArr runs, dense CSR slots[d][64]+deg, 1-node-per-wave
// readlane gather; GEMM is fused per-node via readlane broadcast + LDS W^T.
// Per-node slot cap 64: deg ~ Poisson(16), P(deg>64) < 1e-20.
// Requires N <= 65536 (dst,src packed 16+16 in partArr) - harness N=50000.
#define EPB 1024      // edges per partition chunk (4/thread, 782 chunks)
#define EPT 4         // EPB/256
#define CSTRIDE 16    // ints per cursor slot (64B line-private reservations)

__global__ __launch_bounds__(256) void fused_kernel(
    const float4* __restrict__ x4, short4* __restrict__ xh, int nq,
    const int* __restrict__ ei, int E, int NBK, int CAPB,
    int* __restrict__ cursor, int* __restrict__ deg,
    unsigned int* __restrict__ partArr, unsigned short* __restrict__ slots,
    const float* __restrict__ W, const float* __restrict__ bias,
    const float* __restrict__ beta_p, float* __restrict__ out, int N)
{
    cg::grid_group grid = cg::this_grid();
    // 16KB union: B uses hist[256]+off[256]; C uses c[256]; D uses Wl[4096]f.
    __shared__ int smem[4096];
    const int tid  = threadIdx.x;
    const int bid  = blockIdx.x;
    const int G    = gridDim.x;
    const int gtid = bid * 256 + tid;
    const int gsz  = G * 256;

    // ---- Phase A: zero cursor + pack x -> relu(x)+eps as fp16 ----
    for (int i = gtid; i < NBK * CSTRIDE; i += gsz) cursor[i] = 0;
    for (int i = gtid; i < nq; i += gsz) {
        float4 v = x4[i];
        short4 o;
        o.x = __half_as_short(__float2half_rn(fmaxf(v.x, 0.f) + EPS));
        o.y = __half_as_short(__float2half_rn(fmaxf(v.y, 0.f) + EPS));
        o.z = __half_as_short(__float2half_rn(fmaxf(v.z, 0.f) + EPS));
        o.w = __half_as_short(__float2half_rn(fmaxf(v.w, 0.f) + EPS));
        xh[i] = o;
    }
    __threadfence();
    grid.sync();

    // ---- Phase B: partition edges into 256-node dst buckets ----
    {
        int* hist = smem;
        int* off  = smem + 256;
        int echunks = (E + EPB - 1) / EPB;
        for (int c = bid; c < echunks; c += G) {
            hist[tid] = 0;
            __syncthreads();
            int base = c * EPB;
            int dd[EPT], ss[EPT], bk[EPT], rk[EPT];
            #pragma unroll
            for (int k = 0; k < EPT; ++k) {
                int e = base + k * 256 + tid;
                bk[k] = -1;
                if (e < E) {
                    dd[k] = ei[e];          // dst (coalesced)
                    ss[k] = ei[E + e];      // src (coalesced)
                    bk[k] = dd[k] >> 8;
                    rk[k] = atomicAdd(&hist[bk[k]], 1);   // LDS rank
                }
            }
            __syncthreads();
            int hv = hist[tid];
            if (tid < NBK && hv > 0)
                off[tid] = atomicAdd(&cursor[tid * CSTRIDE], hv);  // line-private
            __syncthreads();
            #pragma unroll
            for (int k = 0; k < EPT; ++k) {
                if (bk[k] >= 0) {
                    int idx = off[bk[k]] + rk[k];
                    if (idx < CAPB)   // astronomically-unlikely overflow: drop
                        partArr[(size_t)bk[k] * CAPB + idx] =
                            ((unsigned int)dd[k] << 16) | (unsigned int)(ss[k] & 0xFFFF);
                }
            }
            __syncthreads();   // protect hist reuse on next grid-stride c
        }
    }
    __threadfence();
    grid.sync();

    // ---- Phase C: build dense CSR slots[d][64] + deg[d], one block/bucket ----
    for (int bkt = bid; bkt < NBK; bkt += G) {
        smem[tid] = 0;
        __syncthreads();
        int cnt = cursor[bkt * CSTRIDE];
        if (cnt > CAPB) cnt = CAPB;
        const unsigned int* pa = partArr + (size_t)bkt * CAPB;
        for (int i = tid; i < cnt; i += 256) {
            unsigned int u = pa[i];                 // coalesced
            int d = u >> 16;
            int r = atomicAdd(&smem[d & 255], 1);   // LDS atomic
            if (r < 64) slots[((size_t)d << 6) + r] = (unsigned short)(u & 0xFFFF);
        }
        __syncthreads();
        int dv = smem[tid];
        deg[(bkt << 8) + tid] = (dv > 64) ? 64 : dv;
        __syncthreads();
    }
    __threadfence();
    grid.sync();

    // ---- Phase D: stage W^T in LDS; 1 node/wave gather + fused GEMM row ----
    float* Wl = (float*)smem;                    // Wl[f*64+j] = W[j][f]
    for (int ti = tid; ti < 1024; ti += 256) {
        float4 wv = ((const float4*)W)[ti];      // j = ti>>4, f = 4*(ti&15)..
        int j = ti >> 4, f0 = (ti & 15) << 2;
        Wl[(f0 + 0) * 64 + j] = wv.x;
        Wl[(f0 + 1) * 64 + j] = wv.y;
        Wl[(f0 + 2) * 64 + j] = wv.z;
        Wl[(f0 + 3) * 64 + j] = wv.w;
    }
    __syncthreads();

    const int lane   = tid & 63;
    const int w      = tid >> 6;
    const float bj   = bias[lane];
    const float beta = beta_p[0];
    const int nch    = (N + 3) >> 2;
    for (int c = bid; c < nch; c += G) {
        int n = (c << 2) + w;
        if (n >= N) continue;                     // no barriers below: safe
        unsigned short raw = slots[((size_t)n << 6) + lane];  // issue first
        int dg = deg[n];                          // overlaps with raw load
        int myid = (lane < dg) ? (int)raw : 0;    // mask AFTER both land

        float acs = 0.0f, act = 0.0f;
        #define ACCV(wv, j) { float m = __half2float(wv); float e = __expf(beta * m); \
                              e = (i + (j) < dg) ? e : 0.0f; \
                              acs += e; act = fmaf(m, e, act); }
        for (int i = 0; i < dg; i += 8) {
            const __half* q0 = (const __half*)xh + (__builtin_amdgcn_readlane(myid, i + 0) << 6);
            const __half* q1 = (const __half*)xh + (__builtin_amdgcn_readlane(myid, i + 1) << 6);
            const __half* q2 = (const __half*)xh + (__builtin_amdgcn_readlane(myid, i + 2) << 6);
            const __half* q3 = (const __half*)xh + (__builtin_amdgcn_readlane(myid, i + 3) << 6);
            const __half* q4 = (const __half*)xh + (__builtin_amdgcn_readlane(myid, i + 4) << 6);
            const __half* q5 = (const __half*)xh + (__builtin_amdgcn_readlane(myid, i + 5) << 6);
            const __half* q6 = (const __half*)xh + (__builtin_amdgcn_readlane(myid, i + 6) << 6);
            const __half* q7 = (const __half*)xh + (__builtin_amdgcn_readlane(myid, i + 7) << 6);
            __half w0 = q0[lane], w1 = q1[lane], w2 = q2[lane], w3 = q3[lane];
            __half w4 = q4[lane], w5 = q5[lane], w6 = q6[lane], w7 = q7[lane];
            ACCV(w0, 0) ACCV(w1, 1) ACCV(w2, 2) ACCV(w3, 3)
            ACCV(w4, 4) ACCV(w5, 5) ACCV(w6, 6) ACCV(w7, 7)
        }
        #undef ACCV
        float h = (dg > 0) ? (act / acs) : 0.0f;  // lane = feature f of node n

        // GEMM row: out[n][lane] = b[lane] + sum_f h[f] * W[lane][f].
        // readlane -> SGPR broadcast; Wl read is 2-way (free) bank pattern.
        float o = bj;
        int hb = __float_as_int(h);
        #pragma unroll 16
        for (int f = 0; f < 64; ++f)
            o = fmaf(__int_as_float(__builtin_amdgcn_readlane(hb, f)),
                     Wl[(f << 6) + lane], o);
        out[(size_t)n * 64 + lane] = o;           // 256B coalesced per wave
    }
}

extern "C" void kernel_launch(void* const* d_in, const int* in_sizes, int n_in,
                              void* d_out, int out_size, void* d_ws, size_t ws_size,
                              hipStream_t stream) {
    const float4* x4    = (const float4*)d_in[0];
    const float*  W     = (const float*)d_in[1];
    const float*  b     = (const float*)d_in[2];
    const float*  betap = (const float*)d_in[3];
    const int*    ei    = (const int*)d_in[4];

    int NT = in_sizes[0];        // N * 64
    int N  = NT / 64;
    int E  = in_sizes[4] / 2;
    int nq = NT / 4;

    int NBK = (N + 255) >> 8;                    // 256-node buckets (196)
    int NP  = NBK << 8;
    int CAPB = (int)(((size_t)2 * E / NBK + 255) & ~(size_t)255);   // ~8192

    // ws layout: cursor[NBK*CSTRIDE] | deg[NP] | partArr[NBK*CAPB] | xh | slots
    size_t curB   = (size_t)NBK * CSTRIDE * 4;
    size_t fixedB = curB + (size_t)NP * 4 + (size_t)NT * 2 + (size_t)NP * 64 * 2;
    if (ws_size < fixedB + (size_t)NBK * CAPB * 4) {
        size_t avail = (ws_size > fixedB) ? (ws_size - fixedB) : 0;
        int fitc = (int)(avail / ((size_t)NBK * 4));
        CAPB = (fitc / 64) * 64;
        if (CAPB <= 0) return;   // workspace unusable (never for this harness)
    }

    char* p = (char*)d_ws;
    int* cursor           = (int*)p;              p += curB;
    int* deg              = (int*)p;              p += (size_t)NP * 4;
    unsigned int* partArr = (unsigned int*)p;     p += (size_t)NBK * CAPB * 4;
    short4* xh            = (short4*)p;           p += (size_t)NT * 2;
    unsigned short* slots = (unsigned short*)p;

    // Cooperative grid sized from a cached occupancy query: capacity
    // violations become impossible by construction (VGPR pressure only
    // shrinks G; grid-stride loops absorb any G >= 1).
    static int gblocks = -1;
    if (gblocks < 0) {
        int mb = 0;
        if (hipOccupancyMaxActiveBlocksPerMultiprocessor(&mb, fused_kernel, 256, 0)
                != hipSuccess || mb <= 0) mb = 2;
        if (mb > 8) mb = 8;
        int ncu = 256;
        hipDeviceProp_t prop;
        int dev = 0;
        if (hipGetDevice(&dev) == hipSuccess &&
            hipGetDeviceProperties(&prop, dev) == hipSuccess)
            ncu = prop.multiProcessorCount;
        gblocks = ncu * mb;
    }

    float* outp = (float*)d_out;
    void* args[] = { (void*)&x4, (void*)&xh, (void*)&nq, (void*)&ei, (void*)&E,
                     (void*)&NBK, (void*)&CAPB, (void*)&cursor, (void*)&deg,
                     (void*)&partArr, (void*)&slots, (void*)&W, (void*)&b,
                     (void*)&betap, (void*)&outp, (void*)&N };
    hipLaunchCooperativeKernel((void*)fused_kernel, dim3(gblocks), dim3(256),
                               args, 0, stream);
}

// Round 6
// 156.482 us; speedup vs baseline: 5.6670x; 5.6670x over previous
//
#include <hip/hip_runtime.h>
#include <hip/hip_fp16.h>

#define EPS 1e-7f
// R0 proven structure (memset, part, build, main) with two local upgrades:
//  - build: 4 sub-blocks/bucket (784 blocks, ~3/CU) with global-atomic slot
//    reservation into zeroed deg; scatter window stays 32KB/bucket (L2-hot).
//  - main: GEMM fused per-node (readlane broadcast + LDS W^T, proven in R5's
//    phase D) - kills the gemm dispatch and the 25.6MB h round-trip.
// Per-node slot cap 64: deg ~ Poisson(16), P(deg>64) < 1e-20.
#define EPB 4096      // edges per P1 block (16/thread)
#define CSTRIDE 16    // ints per cursor slot (64B line-private reservations)
#define SUBB 4        // build sub-blocks per bucket

__device__ __forceinline__ void pack_body(const float4* __restrict__ x4,
                                          short4* __restrict__ xh, int i, int nq) {
    if (i < nq) {
        float4 v = x4[i];
        short4 o;
        o.x = __half_as_short(__float2half_rn(fmaxf(v.x, 0.f) + EPS));
        o.y = __half_as_short(__float2half_rn(fmaxf(v.y, 0.f) + EPS));
        o.z = __half_as_short(__float2half_rn(fmaxf(v.z, 0.f) + EPS));
        o.w = __half_as_short(__float2half_rn(fmaxf(v.w, 0.f) + EPS));
        xh[i] = o;
    }
}

// K1 (pack + partition): blocks [0,packBlocks) pack x->fp16; the rest
// partition edges into 256-node dst-buckets. Per-edge rank via LDS atomic;
// ONE line-private global atomic per (block,bucket) reserves a run.
__global__ __launch_bounds__(256) void part_kernel(const float4* __restrict__ x4,
                                                   short4* __restrict__ xh, int nq,
                                                   int packBlocks,
                                                   const int* __restrict__ ei, int E,
                                                   int CAPB,
                                                   int* __restrict__ cursor,
                                                   unsigned int* __restrict__ partArr) {
    int bb = blockIdx.x;
    int tid = threadIdx.x;
    if (bb < packBlocks) {
        pack_body(x4, xh, bb * 256 + tid, nq);
        return;
    }
    __shared__ int hist[256];
    __shared__ int off[256];
    int blk = bb - packBlocks;
    hist[tid] = 0;
    __syncthreads();

    int base = blk * EPB;
    int dd[16], ss[16], bk[16], rk[16];
    #pragma unroll
    for (int k = 0; k < 16; ++k) {
        int e = base + k * 256 + tid;
        bk[k] = -1;
        if (e < E) {
            dd[k] = ei[e];          // dst (coalesced)
            ss[k] = ei[E + e];      // src (coalesced)
            bk[k] = dd[k] >> 8;
            rk[k] = atomicAdd(&hist[bk[k]], 1);   // LDS atomic -> local rank
        }
    }
    __syncthreads();
    int hv = hist[tid];
    if (hv > 0) off[tid] = atomicAdd(&cursor[tid * CSTRIDE], hv);  // line-private
    __syncthreads();
    #pragma unroll
    for (int k = 0; k < 16; ++k) {
        if (bk[k] >= 0) {
            int idx = off[bk[k]] + rk[k];
            if (idx < CAPB)   // astronomically-unlikely overflow: drop, stay safe
                partArr[(size_t)bk[k] * CAPB + idx] =
                    ((unsigned int)dd[k] << 16) | (unsigned int)(ss[k] & 0xFFFF);
        }
    }
}

// K2: CSR build, 4 sub-blocks per bucket (784 blocks -> ~3/CU, vs R0's 196 at
// <1/CU). Each sub-block owns a quarter of the bucket's partArr run: pass 1
// counts per-node in LDS; ONE global atomic per (sub,node) on zero-initialized
// deg reserves the slot base; pass 2 (L2-hot re-read) places edges at
// base+rank. Scatter window stays 32KB/bucket - L2-resident (the R2 lesson).
__global__ __launch_bounds__(256) void build_kernel(const unsigned int* __restrict__ partArr,
                                                    const int* __restrict__ cursor,
                                                    int CAPB,
                                                    unsigned short* __restrict__ slots,
                                                    int* __restrict__ deg) {
    __shared__ int c[256];
    __shared__ int base[256];
    int tid = threadIdx.x;
    int bkt = blockIdx.x >> 2;
    int sub = blockIdx.x & (SUBB - 1);
    c[tid] = 0;
    __syncthreads();

    int cnt = cursor[bkt * CSTRIDE];
    if (cnt > CAPB) cnt = CAPB;
    int lo = (cnt * sub) >> 2;
    int hi = (cnt * (sub + 1)) >> 2;
    const unsigned int* pa = partArr + (size_t)bkt * CAPB;

    for (int i = lo + tid; i < hi; i += 256)           // pass 1: count
        atomicAdd(&c[(pa[i] >> 16) & 255], 1);
    __syncthreads();
    int cc = c[tid];
    base[tid] = (cc > 0) ? atomicAdd(&deg[(bkt << 8) + tid], cc) : 0;
    c[tid] = 0;                                        // reuse as rank counter
    __syncthreads();
    for (int i = lo + tid; i < hi; i += 256) {         // pass 2: place (L2-hot)
        unsigned int u = pa[i];
        int d = u >> 16;
        int r = base[d & 255] + atomicAdd(&c[d & 255], 1);
        if (r < 64) slots[((size_t)d << 6) + r] = (unsigned short)(u & 0xFFFF);
    }
}

// K3 (gather + softmax + fused GEMM): R0's proven 1-node-per-wave readlane
// batch-8 gather; then out[n][lane] = b[lane] + sum_f h[f]*W[lane][f] via
// readlane broadcast + LDS W^T (proven in R5 phase D). slots/deg loads are
// issued BEFORE the W staging so they overlap it; single barrier precedes any
// early exit (no divergent-barrier hazard).
__global__ __launch_bounds__(256) void main_kernel(const __half* __restrict__ xh,
                                                   const float* __restrict__ beta_p,
                                                   const int* __restrict__ deg,
                                                   const unsigned short* __restrict__ slots,
                                                   const float* __restrict__ W,
                                                   const float* __restrict__ bias,
                                                   float* __restrict__ out, int N) {
    __shared__ float Wl[4096];                    // Wl[f*64+j] = W[j][f]
    int tid  = threadIdx.x;
    int lane = tid & 63;
    int w = tid >> 6;
    int n = blockIdx.x * 4 + w;
    int nc = (n < N) ? n : (N - 1);               // clamp for loads only

    unsigned short raw = slots[((size_t)nc << 6) + lane];  // issue first
    int dg = deg[nc];                                      // overlaps raw load

    #pragma unroll
    for (int kk = 0; kk < 4; ++kk) {              // stage W^T (overlaps above)
        int ti = kk * 256 + tid;
        float4 wv = ((const float4*)W)[ti];       // row j = ti>>4, f0 = 4*(ti&15)
        int j = ti >> 4, f0 = (ti & 15) << 2;
        Wl[(f0 + 0) * 64 + j] = wv.x;
        Wl[(f0 + 1) * 64 + j] = wv.y;
        Wl[(f0 + 2) * 64 + j] = wv.z;
        Wl[(f0 + 3) * 64 + j] = wv.w;
    }
    __syncthreads();                              // only barrier; before exits
    if (n >= N) return;

    float beta = beta_p[0];
    if (dg > 64) dg = 64;
    int myid = (lane < dg) ? (int)raw : 0;        // mask AFTER loads land

    float s = 0.0f, t = 0.0f;
    #define ACCV(wv, j) { float m = __half2float(wv); float e = __expf(beta * m); \
                          e = (i + (j) < dg) ? e : 0.0f;  /* uniform cmp+cndmask */ \
                          s += e; t = fmaf(m, e, t); }
    for (int i = 0; i < dg; i += 8) {
        const __half* q0 = xh + (__builtin_amdgcn_readlane(myid, i + 0) << 6);
        const __half* q1 = xh + (__builtin_amdgcn_readlane(myid, i + 1) << 6);
        const __half* q2 = xh + (__builtin_amdgcn_readlane(myid, i + 2) << 6);
        const __half* q3 = xh + (__builtin_amdgcn_readlane(myid, i + 3) << 6);
        const __half* q4 = xh + (__builtin_amdgcn_readlane(myid, i + 4) << 6);
        const __half* q5 = xh + (__builtin_amdgcn_readlane(myid, i + 5) << 6);
        const __half* q6 = xh + (__builtin_amdgcn_readlane(myid, i + 6) << 6);
        const __half* q7 = xh + (__builtin_amdgcn_readlane(myid, i + 7) << 6);
        __half w0 = q0[lane], w1 = q1[lane], w2 = q2[lane], w3 = q3[lane];
        __half w4 = q4[lane], w5 = q5[lane], w6 = q6[lane], w7 = q7[lane];
        ACCV(w0, 0) ACCV(w1, 1) ACCV(w2, 2) ACCV(w3, 3)
        ACCV(w4, 4) ACCV(w5, 5) ACCV(w6, 6) ACCV(w7, 7)
    }
    #undef ACCV
    float h = (dg > 0) ? (t / s) : 0.0f;          // lane = feature f of node n

    // fused GEMM row: readlane -> SGPR broadcast; Wl stride-64 read is
    // conflict-free (64 consecutive floats across 32 banks, 2-way = free).
    float o = bias[lane];
    int hb = __float_as_int(h);
    #pragma unroll 16
    for (int f = 0; f < 64; ++f)
        o = fmaf(__int_as_float(__builtin_amdgcn_readlane(hb, f)),
                 Wl[(f << 6) + lane], o);
    out[(size_t)n * 64 + lane] = o;               // 256B coalesced per wave
}

extern "C" void kernel_launch(void* const* d_in, const int* in_sizes, int n_in,
                              void* d_out, int out_size, void* d_ws, size_t ws_size,
                              hipStream_t stream) {
    const float* x      = (const float*)d_in[0];
    const float* W      = (const float*)d_in[1];
    const float* b      = (const float*)d_in[2];
    const float* beta_p = (const float*)d_in[3];
    const int*   ei     = (const int*)d_in[4];

    int NT = in_sizes[0];        // N * 64
    int N  = NT / 64;
    int E  = in_sizes[4] / 2;

    int NBK = (N + 255) >> 8;                    // 256-node buckets (196)
    int NP  = NBK << 8;
    int pblocks = (NT / 4 + 255) / 256;
    int eblocks = (E + EPB - 1) / EPB;

    // ws layout: cursor[NBK*CSTRIDE] | deg[NP] | partArr[NBK*CAPB] | xh | slots
    size_t curB   = (size_t)NBK * CSTRIDE * 4;
    size_t fixedB = curB + (size_t)NP * 4 + (size_t)NT * 2 + (size_t)NP * 64 * 2;
    int CAPB = (int)(((size_t)2 * E / NBK + 255) & ~(size_t)255);    // ~8192
    if (ws_size < fixedB + (size_t)NBK * CAPB * 4) {
        size_t avail = (ws_size > fixedB) ? (ws_size - fixedB) : 0;
        int fitc = (int)(avail / ((size_t)NBK * 4));
        CAPB = (fitc / 64) * 64;
        if (CAPB <= 0) return;   // workspace unusable (never for this harness)
    }

    char* p = (char*)d_ws;
    int* cursor           = (int*)p;              p += curB;
    int* deg              = (int*)p;              p += (size_t)NP * 4;
    unsigned int* partArr = (unsigned int*)p;     p += (size_t)NBK * CAPB * 4;
    __half* xh            = (__half*)p;           p += (size_t)NT * 2;
    unsigned short* slots = (unsigned short*)p;

    // one memset covers cursor AND deg (adjacent; deg must start at 0 for the
    // build kernel's atomic slot-base reservation)
    hipMemsetAsync(cursor, 0, curB + (size_t)NP * 4, stream);

    part_kernel<<<pblocks + eblocks, 256, 0, stream>>>(
        (const float4*)x, (short4*)xh, NT / 4, pblocks, ei, E, CAPB, cursor, partArr);

    build_kernel<<<NBK * SUBB, 256, 0, stream>>>(partArr, cursor, CAPB, slots, deg);

    main_kernel<<<(N + 3) / 4, 256, 0, stream>>>(xh, beta_p, deg, slots, W, b,
                                                 (float*)d_out, N);
}

// Round 7
// 135.452 us; speedup vs baseline: 6.5469x; 1.1553x over previous
//
#include <hip/hip_runtime.h>
#include <hip/hip_fp16.h>

#define EPS 1e-7f
// Structure: memset | part(pack+partition) | build | main(gather+softmax+GEMM).
// R6 lesson (rocprof): fused readlane-GEMM had a 16-way LDS write conflict
// (2.4e7 conflict cycles) + 3 instr/MAC. This version fuses the GEMM as the
// PROVEN R0 blocked gemm_kernel pattern (GS=65 padding, <=2-way everywhere)
// over a 32-node block tile, h staged in LDS (never written to global).
// Per-node slot cap 64: deg ~ Poisson(16), P(deg>64) < 1e-20.
#define EPB 4096      // edges per P1 block (16/thread)
#define CSTRIDE 16    // ints per cursor slot (64B line-private reservations)
#define SUBB 4        // build sub-blocks per bucket
#define GS 65         // LDS stride padding (conflict-free)

__device__ __forceinline__ void pack_body(const float4* __restrict__ x4,
                                          short4* __restrict__ xh, int i, int nq) {
    if (i < nq) {
        float4 v = x4[i];
        short4 o;
        o.x = __half_as_short(__float2half_rn(fmaxf(v.x, 0.f) + EPS));
        o.y = __half_as_short(__float2half_rn(fmaxf(v.y, 0.f) + EPS));
        o.z = __half_as_short(__float2half_rn(fmaxf(v.z, 0.f) + EPS));
        o.w = __half_as_short(__float2half_rn(fmaxf(v.w, 0.f) + EPS));
        xh[i] = o;
    }
}

// K1 (pack + partition): blocks [0,packBlocks) pack x->fp16; the rest
// partition edges into 256-node dst-buckets. Per-edge rank via LDS atomic;
// ONE line-private global atomic per (block,bucket) reserves a run.
__global__ __launch_bounds__(256) void part_kernel(const float4* __restrict__ x4,
                                                   short4* __restrict__ xh, int nq,
                                                   int packBlocks,
                                                   const int* __restrict__ ei, int E,
                                                   int CAPB,
                                                   int* __restrict__ cursor,
                                                   unsigned int* __restrict__ partArr) {
    int bb = blockIdx.x;
    int tid = threadIdx.x;
    if (bb < packBlocks) {
        pack_body(x4, xh, bb * 256 + tid, nq);
        return;
    }
    __shared__ int hist[256];
    __shared__ int off[256];
    int blk = bb - packBlocks;
    hist[tid] = 0;
    __syncthreads();

    int base = blk * EPB;
    int dd[16], ss[16], bk[16], rk[16];
    #pragma unroll
    for (int k = 0; k < 16; ++k) {
        int e = base + k * 256 + tid;
        bk[k] = -1;
        if (e < E) {
            dd[k] = ei[e];          // dst (coalesced)
            ss[k] = ei[E + e];      // src (coalesced)
            bk[k] = dd[k] >> 8;
            rk[k] = atomicAdd(&hist[bk[k]], 1);   // LDS atomic -> local rank
        }
    }
    __syncthreads();
    int hv = hist[tid];
    if (hv > 0) off[tid] = atomicAdd(&cursor[tid * CSTRIDE], hv);  // line-private
    __syncthreads();
    #pragma unroll
    for (int k = 0; k < 16; ++k) {
        if (bk[k] >= 0) {
            int idx = off[bk[k]] + rk[k];
            if (idx < CAPB)   // astronomically-unlikely overflow: drop, stay safe
                partArr[(size_t)bk[k] * CAPB + idx] =
                    ((unsigned int)dd[k] << 16) | (unsigned int)(ss[k] & 0xFFFF);
        }
    }
}

// K2: CSR build, 4 sub-blocks per bucket (784 blocks -> ~3/CU). Pass 1 counts
// per-node in LDS; ONE global atomic per (sub,node) on zero-initialized deg
// reserves the slot base; pass 2 (L2-hot re-read) places edges at base+rank.
// Scatter window stays 32KB/bucket - L2-resident (the R2 lesson).
__global__ __launch_bounds__(256) void build_kernel(const unsigned int* __restrict__ partArr,
                                                    const int* __restrict__ cursor,
                                                    int CAPB,
                                                    unsigned short* __restrict__ slots,
                                                    int* __restrict__ deg) {
    __shared__ int c[256];
    __shared__ int base[256];
    int tid = threadIdx.x;
    int bkt = blockIdx.x >> 2;
    int sub = blockIdx.x & (SUBB - 1);
    c[tid] = 0;
    __syncthreads();

    int cnt = cursor[bkt * CSTRIDE];
    if (cnt > CAPB) cnt = CAPB;
    int lo = (cnt * sub) >> 2;
    int hi = (cnt * (sub + 1)) >> 2;
    const unsigned int* pa = partArr + (size_t)bkt * CAPB;

    for (int i = lo + tid; i < hi; i += 256)           // pass 1: count
        atomicAdd(&c[(pa[i] >> 16) & 255], 1);
    __syncthreads();
    int cc = c[tid];
    base[tid] = (cc > 0) ? atomicAdd(&deg[(bkt << 8) + tid], cc) : 0;
    c[tid] = 0;                                        // reuse as rank counter
    __syncthreads();
    for (int i = lo + tid; i < hi; i += 256) {         // pass 2: place (L2-hot)
        unsigned int u = pa[i];
        int d = u >> 16;
        int r = base[d & 255] + atomicAdd(&c[d & 255], 1);
        if (r < 64) slots[((size_t)d << 6) + r] = (unsigned short)(u & 0xFFFF);
    }
}

// K3 (gather + softmax + blocked GEMM): 512 threads = 8 waves own 32 nodes
// (4/wave as 2 INTERLEAVED pairs -> 16 concurrent gather loads, 2x the MLP of
// batch-8). h goes to hl[32][GS] in LDS (never to global). After one barrier
// the block runs R0's proven gemm pattern: Wt[64][GS] staged conflict-free,
// scalar b32 reads, 1 row x 4 cols per thread. All LDS patterns <=2-way by
// bank arithmetic (write hl: 64 consecutive; read hl[r][d]: broadcast x32
// banks; Wt writes/reads: the GS=65 proven layout).
__global__ __launch_bounds__(512) void main_kernel(const __half* __restrict__ xh,
                                                   const float* __restrict__ beta_p,
                                                   const int* __restrict__ deg,
                                                   const unsigned short* __restrict__ slots,
                                                   const float* __restrict__ W,
                                                   const float* __restrict__ bias,
                                                   float* __restrict__ out, int N) {
    __shared__ float hl[32 * GS];                 // 8.3KB
    __shared__ float Wt[64 * GS];                 // 16.6KB  Wt[f][j] = W[j][f]
    int tid  = threadIdx.x;
    int lane = tid & 63;
    int w    = tid >> 6;                          // wave 0..7
    int n0   = blockIdx.x * 32;
    float beta = beta_p[0];

    // stage W^T (R0 gemm pattern, proven conflict-free); overlaps gather below
    #pragma unroll
    for (int kk = 0; kk < 2; ++kk) {
        int i4 = kk * 512 + tid;
        int rj = i4 >> 4;
        int d0 = (i4 & 15) * 4;
        float4 wv = *(const float4*)(W + (size_t)i4 * 4);
        Wt[(d0 + 0) * GS + rj] = wv.x;
        Wt[(d0 + 1) * GS + rj] = wv.y;
        Wt[(d0 + 2) * GS + rj] = wv.z;
        Wt[(d0 + 3) * GS + rj] = wv.w;
    }

    #pragma unroll
    for (int pp = 0; pp < 2; ++pp) {
        int la = (w << 2) + (pp << 1);            // local rows la, la+1
        int na = n0 + la, nb = na + 1;
        int nca = (na < N) ? na : (N - 1);        // clamp loads only
        int ncb = (nb < N) ? nb : (N - 1);
        unsigned short rawA = slots[((size_t)nca << 6) + lane];  // issue early
        unsigned short rawB = slots[((size_t)ncb << 6) + lane];
        int dgA = deg[nca];                       // overlaps raw loads
        int dgB = deg[ncb];
        if (dgA > 64) dgA = 64;
        if (dgB > 64) dgB = 64;
        int idA = (lane < dgA) ? (int)rawA : 0;   // mask AFTER loads land
        int idB = (lane < dgB) ? (int)rawB : 0;
        int dgm = (dgA > dgB) ? dgA : dgB;

        float sA = 0.f, tA = 0.f, sB = 0.f, tB = 0.f;
        #define ACCV(wv, j, dgX, sX, tX) { float m = __half2float(wv);          \
            float e = __expf(beta * m); e = (i + (j) < dgX) ? e : 0.0f;         \
            sX += e; tX = fmaf(m, e, tX); }
        for (int i = 0; i < dgm; i += 8) {
            const __half* a0 = xh + (__builtin_amdgcn_readlane(idA, i + 0) << 6);
            const __half* a1 = xh + (__builtin_amdgcn_readlane(idA, i + 1) << 6);
            const __half* a2 = xh + (__builtin_amdgcn_readlane(idA, i + 2) << 6);
            const __half* a3 = xh + (__builtin_amdgcn_readlane(idA, i + 3) << 6);
            const __half* a4 = xh + (__builtin_amdgcn_readlane(idA, i + 4) << 6);
            const __half* a5 = xh + (__builtin_amdgcn_readlane(idA, i + 5) << 6);
            const __half* a6 = xh + (__builtin_amdgcn_readlane(idA, i + 6) << 6);
            const __half* a7 = xh + (__builtin_amdgcn_readlane(idA, i + 7) << 6);
            const __half* b0 = xh + (__builtin_amdgcn_readlane(idB, i + 0) << 6);
            const __half* b1 = xh + (__builtin_amdgcn_readlane(idB, i + 1) << 6);
            const __half* b2 = xh + (__builtin_amdgcn_readlane(idB, i + 2) << 6);
            const __half* b3 = xh + (__builtin_amdgcn_readlane(idB, i + 3) << 6);
            const __half* b4 = xh + (__builtin_amdgcn_readlane(idB, i + 4) << 6);
            const __half* b5 = xh + (__builtin_amdgcn_readlane(idB, i + 5) << 6);
            const __half* b6 = xh + (__builtin_amdgcn_readlane(idB, i + 6) << 6);
            const __half* b7 = xh + (__builtin_amdgcn_readlane(idB, i + 7) << 6);
            __half wa0 = a0[lane], wa1 = a1[lane], wa2 = a2[lane], wa3 = a3[lane];
            __half wa4 = a4[lane], wa5 = a5[lane], wa6 = a6[lane], wa7 = a7[lane];
            __half wb0 = b0[lane], wb1 = b1[lane], wb2 = b2[lane], wb3 = b3[lane];
            __half wb4 = b4[lane], wb5 = b5[lane], wb6 = b6[lane], wb7 = b7[lane];
            ACCV(wa0, 0, dgA, sA, tA) ACCV(wa1, 1, dgA, sA, tA)
            ACCV(wa2, 2, dgA, sA, tA) ACCV(wa3, 3, dgA, sA, tA)
            ACCV(wa4, 4, dgA, sA, tA) ACCV(wa5, 5, dgA, sA, tA)
            ACCV(wa6, 6, dgA, sA, tA) ACCV(wa7, 7, dgA, sA, tA)
            ACCV(wb0, 0, dgB, sB, tB) ACCV(wb1, 1, dgB, sB, tB)
            ACCV(wb2, 2, dgB, sB, tB) ACCV(wb3, 3, dgB, sB, tB)
            ACCV(wb4, 4, dgB, sB, tB) ACCV(wb5, 5, dgB, sB, tB)
            ACCV(wb6, 6, dgB, sB, tB) ACCV(wb7, 7, dgB, sB, tB)
        }
        #undef ACCV
        hl[la * GS + lane]       = (dgA > 0) ? (tA / sA) : 0.0f;  // 64 consec: free
        hl[(la + 1) * GS + lane] = (dgB > 0) ? (tB / sB) : 0.0f;
    }
    __syncthreads();                              // single barrier, all threads

    // blocked GEMM (R0 gemm_kernel pattern): thread = 1 row x 4 cols
    int c4 = tid & 15;                            // col quad
    int r  = tid >> 4;                            // row 0..31
    float4 bv = *(const float4*)(bias + c4 * 4);
    float a0 = bv.x, a1 = bv.y, a2 = bv.z, a3 = bv.w;
    #pragma unroll 8
    for (int d = 0; d < 64; ++d) {
        float h  = hl[r * GS + d];                // 16-lane broadcast, 32 banks
        float w0 = Wt[d * GS + c4 * 4 + 0];       // proven GS=65 pattern
        float w1 = Wt[d * GS + c4 * 4 + 1];
        float w2 = Wt[d * GS + c4 * 4 + 2];
        float w3 = Wt[d * GS + c4 * 4 + 3];
        a0 = fmaf(h, w0, a0); a1 = fmaf(h, w1, a1);
        a2 = fmaf(h, w2, a2); a3 = fmaf(h, w3, a3);
    }
    int row = n0 + r;
    if (row < N)
        *(float4*)(out + (size_t)row * 64 + c4 * 4) = make_float4(a0, a1, a2, a3);
}

extern "C" void kernel_launch(void* const* d_in, const int* in_sizes, int n_in,
                              void* d_out, int out_size, void* d_ws, size_t ws_size,
                              hipStream_t stream) {
    const float* x      = (const float*)d_in[0];
    const float* W      = (const float*)d_in[1];
    const float* b      = (const float*)d_in[2];
    const float* beta_p = (const float*)d_in[3];
    const int*   ei     = (const int*)d_in[4];

    int NT = in_sizes[0];        // N * 64
    int N  = NT / 64;
    int E  = in_sizes[4] / 2;

    int NBK = (N + 255) >> 8;                    // 256-node buckets (196)
    int NP  = NBK << 8;
    int pblocks = (NT / 4 + 255) / 256;
    int eblocks = (E + EPB - 1) / EPB;

    // ws layout: cursor[NBK*CSTRIDE] | deg[NP] | partArr[NBK*CAPB] | xh | slots
    size_t curB   = (size_t)NBK * CSTRIDE * 4;
    size_t fixedB = curB + (size_t)NP * 4 + (size_t)NT * 2 + (size_t)NP * 64 * 2;
    int CAPB = (int)(((size_t)2 * E / NBK + 255) & ~(size_t)255);    // ~8192
    if (ws_size < fixedB + (size_t)NBK * CAPB * 4) {
        size_t avail = (ws_size > fixedB) ? (ws_size - fixedB) : 0;
        int fitc = (int)(avail / ((size_t)NBK * 4));
        CAPB = (fitc / 64) * 64;
        if (CAPB <= 0) return;   // workspace unusable (never for this harness)
    }

    char* p = (char*)d_ws;
    int* cursor           = (int*)p;              p += curB;
    int* deg              = (int*)p;              p += (size_t)NP * 4;
    unsigned int* partArr = (unsigned int*)p;     p += (size_t)NBK * CAPB * 4;
    __half* xh            = (__half*)p;           p += (size_t)NT * 2;
    unsigned short* slots = (unsigned short*)p;

    // one memset covers cursor AND deg (adjacent; deg must start at 0 for the
    // build kernel's atomic slot-base reservation)
    hipMemsetAsync(cursor, 0, curB + (size_t)NP * 4, stream);

    part_kernel<<<pblocks + eblocks, 256, 0, stream>>>(
        (const float4*)x, (short4*)xh, NT / 4, pblocks, ei, E, CAPB, cursor, partArr);

    build_kernel<<<NBK * SUBB, 256, 0, stream>>>(partArr, cursor, CAPB, slots, deg);

    main_kernel<<<(N + 31) / 32, 512, 0, stream>>>(xh, beta_p, deg, slots, W, b,
                                                   (float*)d_out, N);
}